// Round 17
// baseline (2522.115 us; speedup 1.0000x reference)
//
#include <hip/hip_runtime.h>

typedef unsigned short u16;
typedef float f32x4 __attribute__((ext_vector_type(4)));
typedef short s16x8 __attribute__((ext_vector_type(8)));

#define T_TOK   16448L   // 257*64
#define D_DIM   768L
#define H_DIM   3072L
#define E_NUM   8L
#define M_PAD   16640L   // 65*256 ; halves: A=8192 rows (32 tiles), B=8448 rows (33 tiles)

// ---------- helpers ----------
__device__ __forceinline__ u16 f2bf(float f){
  unsigned u = __float_as_uint(f);
  u = u + 0x7FFFu + ((u >> 16) & 1u);          // RNE
  return (u16)(u >> 16);
}
__device__ __forceinline__ unsigned f2bf2(float a, float b){
  return (unsigned)f2bf(a) | ((unsigned)f2bf(b) << 16);
}

__device__ __forceinline__ void gload_lds16(const u16* g, u16* s){
  __builtin_amdgcn_global_load_lds((const __attribute__((address_space(1))) void*)g,
                                   (__attribute__((address_space(3))) void*)s,
                                   16, 0, 0);
}

// bijective XCD chunking (m204)
__device__ __forceinline__ int xcd_chunk(int idx, int n){
  const int q = n >> 3, r = n & 7, x = idx & 7;
  return (x < r ? x*(q+1) : r*(q+1) + (x-r)*q) + (idx >> 3);
}

// ---------- merged prologue: conv x / conv W1 / conv W2 / router (r14, verified) ----------
__global__ __launch_bounds__(256) void k_pro(const float* __restrict__ x,
                                             const float* __restrict__ W1,
                                             const float* __restrict__ W2,
                                             const float* __restrict__ Wr,
                                             const float* __restrict__ br,
                                             u16* __restrict__ xb,
                                             u16* __restrict__ w1b,
                                             u16* __restrict__ w2b,
                                             float* __restrict__ probs){
  const int bx = (int)blockIdx.x, tid = threadIdx.x;
  if (bx < 6240){
    const long base = ((long)bx*256 + tid) << 3;
    uint4 o;
    if (base < T_TOK*D_DIM){
      const float4 f0 = *(const float4*)(x + base);
      const float4 f1 = *(const float4*)(x + base + 4);
      o.x = f2bf2(f0.x, f0.y); o.y = f2bf2(f0.z, f0.w);
      o.z = f2bf2(f1.x, f1.y); o.w = f2bf2(f1.z, f1.w);
    } else { o.x = o.y = o.z = o.w = 0u; }
    *(uint4*)(xb + base) = o;
  } else if (bx < 24672){
    const int  wsel = (bx < 15456) ? 0 : 1;
    const long base = ((long)(bx - (wsel ? 15456 : 6240))*256 + tid) << 3;
    const float* src = wsel ? W2 : W1;
    u16* dst = wsel ? w2b : w1b;
    const float4 f0 = *(const float4*)(src + base);
    const float4 f1 = *(const float4*)(src + base + 4);
    uint4 o;
    o.x = f2bf2(f0.x, f0.y); o.y = f2bf2(f0.z, f0.w);
    o.z = f2bf2(f1.x, f1.y); o.w = f2bf2(f1.z, f1.w);
    *(uint4*)(dst + base) = o;
  } else {
    const int w = (int)(((long)(bx - 24672)*256 + tid) >> 6);
    const int lane = tid & 63;
    if (w >= (int)T_TOK) return;
    const float* xr = x + (long)w * D_DIM;
    float l[8];
#pragma unroll
    for (int e = 0; e < 8; ++e) l[e] = 0.f;
#pragma unroll
    for (int c = 0; c < 3; ++c){
      const float4 xv = *(const float4*)(xr + c*256 + lane*4);
#pragma unroll
      for (int e = 0; e < 8; ++e){
        const float4 wv = *(const float4*)(Wr + (long)e*D_DIM + c*256 + lane*4);
        l[e] += xv.x*wv.x + xv.y*wv.y + xv.z*wv.z + xv.w*wv.w;
      }
    }
#pragma unroll
    for (int e = 0; e < 8; ++e){
#pragma unroll
      for (int off = 32; off > 0; off >>= 1) l[e] += __shfl_xor(l[e], off);
      l[e] += br[e];
    }
    float m = l[0];
#pragma unroll
    for (int e = 1; e < 8; ++e) m = fmaxf(m, l[e]);
    float s = 0.f;
#pragma unroll
    for (int e = 0; e < 8; ++e){ l[e] = __expf(l[e] - m); s += l[e]; }
    const float inv = 1.f / s;
    if (lane == 0){
      float4 p0 = { l[0]*inv, l[1]*inv, l[2]*inv, l[3]*inv };
      float4 p1 = { l[4]*inv, l[5]*inv, l[6]*inv, l[7]*inv };
      *(float4*)(probs + (long)w*8)     = p0;
      *(float4*)(probs + (long)w*8 + 4) = p1;
    }
  }
}

// read one 16-row MFMA fragment: rows rbase..rbase+15, logical k-chunk c (0..7)
__device__ __forceinline__ s16x8 ld_frag(const u16* S, int rbase, int c, int ln){
  const int r = rbase + ln;
  return *(const s16x8*)(S + (r << 6) + ((c ^ (r & 7)) << 3));
}

// ---------- 256x256 GEMM, BK=64, SINGLE 64 KB buffer (2 blocks/CU TLP) ----------
// m97-style: stage -> __syncthreads (drain) -> unbroken 24 ds_read + 64 MFMA ->
// __syncthreads. Per-tile drain stalls are hidden by the co-resident sibling
// block (m114 wave-level overlap), not by in-block pipelining.
// LDS[r][s] = Gsrc[r][s ^ (r&7)] (pre-swizzled source, lane-linear dest);
// readers apply the same involution. Proven conflict-free (r6).
__device__ __forceinline__ void gemm256(const u16* __restrict__ Ag, long lda,
                                        const u16* __restrict__ Bg, long ldb,
                                        int NT, u16* lds, int tid,
                                        f32x4 (&acc)[8][4]){
  const int l  = tid & 63, w = tid >> 6;
  const int wr = w >> 2,  wc = w & 3;
  const int g4 = l >> 4,  ln = l & 15;

  // hoisted staging pointers (advance by 64 elems per K-tile)
  const int rw = l >> 3;
  const int c8 = (l & 7) ^ rw;
  const u16* pA = Ag + (long)(w*8 + rw) * lda + c8*8;
  const u16* pB = Bg + (long)(w*8 + rw) * ldb + c8*8;
  const long sA = 64 * lda, sB = 64 * ldb;     // 64-row strides (uniform -> SGPR)
  u16* dA = lds + w*512;                       // A at [0, 16384) elems
  u16* dB = lds + 16384 + w*512;               // B at [16384, 32768)

  for (int kt = 0; kt < NT; ++kt){
    // stage tile kt into the single buffer (__syncthreads drains vmcnt)
    gload_lds16(pA,        dA);
    gload_lds16(pA +   sA, dA + 4096);
    gload_lds16(pA + 2*sA, dA + 8192);
    gload_lds16(pA + 3*sA, dA + 12288);
    gload_lds16(pB,        dB);
    gload_lds16(pB +   sB, dB + 4096);
    gload_lds16(pB + 2*sB, dB + 8192);
    gload_lds16(pB + 3*sB, dB + 12288);
    pA += 64; pB += 64;
    __syncthreads();

    // one unbroken compiler-scheduled body: 24 ds_read_b128 + 64 MFMA
    const u16* As = lds;
    const u16* Bs = lds + 16384;
    s16x8 a0[8], b0[4], a1[8], b1[4];
#pragma unroll
    for (int ni = 0; ni < 4; ++ni) b0[ni] = ld_frag(Bs, wc*64 + ni*16, g4, ln);
#pragma unroll
    for (int mi = 0; mi < 8; ++mi) a0[mi] = ld_frag(As, wr*128 + mi*16, g4, ln);
#pragma unroll
    for (int mi = 0; mi < 8; ++mi)
#pragma unroll
      for (int ni = 0; ni < 4; ++ni)
        acc[mi][ni] = __builtin_amdgcn_mfma_f32_16x16x32_bf16(a0[mi], b0[ni], acc[mi][ni], 0, 0, 0);
#pragma unroll
    for (int ni = 0; ni < 4; ++ni) b1[ni] = ld_frag(Bs, wc*64 + ni*16, 4 + g4, ln);
#pragma unroll
    for (int mi = 0; mi < 8; ++mi) a1[mi] = ld_frag(As, wr*128 + mi*16, 4 + g4, ln);
#pragma unroll
    for (int mi = 0; mi < 8; ++mi)
#pragma unroll
      for (int ni = 0; ni < 4; ++ni)
        acc[mi][ni] = __builtin_amdgcn_mfma_f32_16x16x32_bf16(a1[mi], b1[ni], acc[mi][ni], 0, 0, 0);
    __syncthreads();
  }
}

// ---------- paired dispatch: g2(e2, one token-half) + g1(e1, other half) ----------
__global__ __launch_bounds__(512, 2) void k_pair(const u16* __restrict__ xb,
                                                 const u16* __restrict__ w1b,
                                                 const float* __restrict__ b1,
                                                 const u16* __restrict__ w2b,
                                                 const float* __restrict__ b2,
                                                 const float* __restrict__ probs,
                                                 float* __restrict__ out,
                                                 const u16* __restrict__ hbR,
                                                 u16* __restrict__ hbW,
                                                 int e2, int t02,
                                                 int e1, int t01, int mt1, int n2){
  __shared__ alignas(16) u16 lds[32768];   // 64 KiB single buffer: A | B
  const int tid = threadIdx.x;
  const int l  = tid & 63, w = tid >> 6;
  const int wr = w >> 2,  wc = w & 3;
  const int g4 = l >> 4,  ln = l & 15;
  const int bx = (int)blockIdx.x;
  f32x4 acc[8][4] = {};

  if (bx < n2){
    // ---- g2: XCD-chunked, y-fastest (3 N-tiles share the A-panel) ----
    const int wg = xcd_chunk(bx, n2);
    const int tx = wg / 3, ty = wg % 3;
    const int m0 = tx << 8, n0 = ty << 8;
    gemm256(hbR + (long)m0 * H_DIM, H_DIM,
            w2b + ((long)e2 * D_DIM + n0) * H_DIM, H_DIM,
            48, lds, tid, acc);
    float bias[4];
#pragma unroll
    for (int ni = 0; ni < 4; ++ni) bias[ni] = b2[(long)e2*D_DIM + n0 + wc*64 + ni*16 + ln];
#pragma unroll
    for (int mi = 0; mi < 8; ++mi){
#pragma unroll
      for (int j = 0; j < 4; ++j){
        const int gt = t02 + m0 + wr*128 + mi*16 + g4*4 + j;
        if (gt < (int)T_TOK){
          const float p = probs[(long)gt*8 + e2];
          float* dst = out + (long)gt * D_DIM + n0 + wc*64;
#pragma unroll
          for (int ni = 0; ni < 4; ++ni){
            const float v = p * (acc[mi][ni][j] + bias[ni]);
            if (e2 == 0) dst[ni*16 + ln] = v;
            else         dst[ni*16 + ln] += v;
          }
        }
      }
    }
  } else {
    // ---- g1: x-fastest chunk (B-panel reuse along chunk) ----
    const int n1 = (int)gridDim.x - n2;
    const int wg = xcd_chunk(bx - n2, n1);
    const int tx = wg % mt1, ty = wg / mt1;
    const int m0 = tx << 8, n0 = ty << 8;
    gemm256(xb + (long)(t01 + m0) * D_DIM, D_DIM,
            w1b + ((long)e1 * H_DIM + n0) * D_DIM, D_DIM,
            12, lds, tid, acc);
    float bias[4];
#pragma unroll
    for (int ni = 0; ni < 4; ++ni) bias[ni] = b1[(long)e1*H_DIM + n0 + wc*64 + ni*16 + ln];
#pragma unroll
    for (int mi = 0; mi < 8; ++mi){
#pragma unroll
      for (int j = 0; j < 4; ++j){
        const int r = m0 + wr*128 + mi*16 + g4*4 + j;     // half-local row
        u16* dst = hbW + (long)r * H_DIM + n0 + wc*64;
#pragma unroll
        for (int ni = 0; ni < 4; ++ni){
          const float v  = acc[mi][ni][j] + bias[ni];
          const float gl = v / (1.0f + __expf(-1.702f * v));  // quick_gelu
          dst[ni*16 + ln] = f2bf(gl);
        }
      }
    }
  }
}

// ---------- final dispatch: g2(7, half B) split-K=2, atomicAdd (starved dispatch) ----------
__global__ __launch_bounds__(512, 2) void k_g2split(const u16* __restrict__ w2b,
                                                    const float* __restrict__ b2,
                                                    const float* __restrict__ probs,
                                                    float* __restrict__ out,
                                                    const u16* __restrict__ hbR,
                                                    int e2, int t02, int n2){
  __shared__ alignas(16) u16 lds[32768];
  const int tid = threadIdx.x;
  const int l  = tid & 63, w = tid >> 6;
  const int wr = w >> 2,  wc = w & 3;
  const int g4 = l >> 4,  ln = l & 15;
  f32x4 acc[8][4] = {};

  const int wg = xcd_chunk((int)blockIdx.x, n2);
  const int ty = wg % 3;
  const int sp = (wg / 3) & 1;
  const int tx = wg / 6;
  const int m0 = tx << 8, n0 = ty << 8;
  gemm256(hbR + (long)m0 * H_DIM + sp*1536, H_DIM,
          w2b + ((long)e2 * D_DIM + n0) * H_DIM + sp*1536, H_DIM,
          24, lds, tid, acc);
  float bias[4];
#pragma unroll
  for (int ni = 0; ni < 4; ++ni)
    bias[ni] = (sp == 0) ? b2[(long)e2*D_DIM + n0 + wc*64 + ni*16 + ln] : 0.f;
#pragma unroll
  for (int mi = 0; mi < 8; ++mi){
#pragma unroll
    for (int j = 0; j < 4; ++j){
      const int gt = t02 + m0 + wr*128 + mi*16 + g4*4 + j;
      if (gt < (int)T_TOK){
        const float p = probs[(long)gt*8 + e2];
        float* dst = out + (long)gt * D_DIM + n0 + wc*64;
#pragma unroll
        for (int ni = 0; ni < 4; ++ni)
          atomicAdd(&dst[ni*16 + ln], p * (acc[mi][ni][j] + bias[ni]));
      }
    }
  }
}

// ---------- host ----------
extern "C" void kernel_launch(void* const* d_in, const int* in_sizes, int n_in,
                              void* d_out, int out_size, void* d_ws, size_t ws_size,
                              hipStream_t stream){
  const float* x  = (const float*)d_in[0];
  const float* W1 = (const float*)d_in[1];
  const float* b1 = (const float*)d_in[2];
  const float* W2 = (const float*)d_in[3];
  const float* b2 = (const float*)d_in[4];
  const float* Wr = (const float*)d_in[5];
  const float* br = (const float*)d_in[6];
  float* out = (float*)d_out;

  char* ws = (char*)d_ws;
  size_t off = 0;
  auto carve = [&](size_t bytes)->void*{
    void* p = ws + off; off += (bytes + 255) & ~(size_t)255; return p;
  };
  u16*   xb    = (u16*)  carve((size_t)M_PAD * D_DIM * 2);
  u16*   w1b   = (u16*)  carve((size_t)E_NUM * H_DIM * D_DIM * 2);
  u16*   w2b   = (u16*)  carve((size_t)E_NUM * D_DIM * H_DIM * 2);
  float* probs = (float*)carve((size_t)T_TOK * E_NUM * 4);
  u16*   hbA   = (u16*)  carve((size_t)8192 * H_DIM * 2);   // tokens [0, 8192)
  u16*   hbB   = (u16*)  carve((size_t)8448 * H_DIM * 2);   // tokens [8192, 16640)

  // merged prologue: conv x/W1/W2 + router in one dispatch
  k_pro<<<dim3(28784), dim3(256), 0, stream>>>(x, W1, W2, Wr, br, xb, w1b, w2b, probs);

  const int MTA = 32, MTB = 33;      // 256-row tile counts per token-half
  const int T0A = 0,  T0B = 8192;

  auto pair = [&](int e2, const u16* hbR, int t02, int mt2,
                  int e1, u16* hbW, int t01, int mt1){
    const int n2 = mt2 * 3;
    const int n1 = mt1 * 12;
    k_pair<<<dim3((unsigned)(n2 + n1)), dim3(512), 0, stream>>>(
        xb, w1b, b1, w2b, b2, probs, out, hbR, hbW,
        e2, t02, e1, t01, mt1, n2);
  };

  // ping-pong: D0: g1(0,A); D(2e+1): g2(e,A)+g1(e,B); D(2e+2): g2(e,B)+g1(e+1,A)
  pair(0, nullptr, 0, 0, 0, hbA, T0A, MTA);
  for (int e = 0; e < 8; ++e){
    pair(e, hbA, T0A, MTA, e, hbB, T0B, MTB);
    if (e < 7) pair(e, hbB, T0B, MTB, e + 1, hbA, T0A, MTA);
  }
  // D16: g2(7,B) alone -> split-K=2 + atomics (dedicated kernel, k_pair untouched)
  k_g2split<<<dim3((unsigned)(MTB * 6)), dim3(512), 0, stream>>>(
      w2b, b2, probs, out, hbB, 7, T0B, MTB * 6);
}

// Round 18
// 1966.547 us; speedup vs baseline: 1.2825x; 1.2825x over previous
//
#include <hip/hip_runtime.h>

typedef unsigned short u16;
typedef float f32x4 __attribute__((ext_vector_type(4)));
typedef short s16x8 __attribute__((ext_vector_type(8)));

#define T_TOK   16448L   // 257*64
#define D_DIM   768L
#define H_DIM   3072L
#define E_NUM   8L
#define M_PAD   16640L   // 65*256 ; halves: A=8192 rows (32 tiles), B=8448 rows (33 tiles)

// ---------- helpers ----------
__device__ __forceinline__ u16 f2bf(float f){
  unsigned u = __float_as_uint(f);
  u = u + 0x7FFFu + ((u >> 16) & 1u);          // RNE
  return (u16)(u >> 16);
}
__device__ __forceinline__ unsigned f2bf2(float a, float b){
  return (unsigned)f2bf(a) | ((unsigned)f2bf(b) << 16);
}

__device__ __forceinline__ void gload_lds16(const u16* g, u16* s){
  __builtin_amdgcn_global_load_lds((const __attribute__((address_space(1))) void*)g,
                                   (__attribute__((address_space(3))) void*)s,
                                   16, 0, 0);
}

// bijective XCD chunking (m204)
__device__ __forceinline__ int xcd_chunk(int idx, int n){
  const int q = n >> 3, r = n & 7, x = idx & 7;
  return (x < r ? x*(q+1) : r*(q+1) + (x-r)*q) + (idx >> 3);
}

// ---------- merged prologue: conv x / conv W1 / conv W2 / router (r14, verified) ----------
__global__ __launch_bounds__(256) void k_pro(const float* __restrict__ x,
                                             const float* __restrict__ W1,
                                             const float* __restrict__ W2,
                                             const float* __restrict__ Wr,
                                             const float* __restrict__ br,
                                             u16* __restrict__ xb,
                                             u16* __restrict__ w1b,
                                             u16* __restrict__ w2b,
                                             float* __restrict__ probs){
  const int bx = (int)blockIdx.x, tid = threadIdx.x;
  if (bx < 6240){
    const long base = ((long)bx*256 + tid) << 3;
    uint4 o;
    if (base < T_TOK*D_DIM){
      const float4 f0 = *(const float4*)(x + base);
      const float4 f1 = *(const float4*)(x + base + 4);
      o.x = f2bf2(f0.x, f0.y); o.y = f2bf2(f0.z, f0.w);
      o.z = f2bf2(f1.x, f1.y); o.w = f2bf2(f1.z, f1.w);
    } else { o.x = o.y = o.z = o.w = 0u; }
    *(uint4*)(xb + base) = o;
  } else if (bx < 24672){
    const int  wsel = (bx < 15456) ? 0 : 1;
    const long base = ((long)(bx - (wsel ? 15456 : 6240))*256 + tid) << 3;
    const float* src = wsel ? W2 : W1;
    u16* dst = wsel ? w2b : w1b;
    const float4 f0 = *(const float4*)(src + base);
    const float4 f1 = *(const float4*)(src + base + 4);
    uint4 o;
    o.x = f2bf2(f0.x, f0.y); o.y = f2bf2(f0.z, f0.w);
    o.z = f2bf2(f1.x, f1.y); o.w = f2bf2(f1.z, f1.w);
    *(uint4*)(dst + base) = o;
  } else {
    const int w = (int)(((long)(bx - 24672)*256 + tid) >> 6);
    const int lane = tid & 63;
    if (w >= (int)T_TOK) return;
    const float* xr = x + (long)w * D_DIM;
    float l[8];
#pragma unroll
    for (int e = 0; e < 8; ++e) l[e] = 0.f;
#pragma unroll
    for (int c = 0; c < 3; ++c){
      const float4 xv = *(const float4*)(xr + c*256 + lane*4);
#pragma unroll
      for (int e = 0; e < 8; ++e){
        const float4 wv = *(const float4*)(Wr + (long)e*D_DIM + c*256 + lane*4);
        l[e] += xv.x*wv.x + xv.y*wv.y + xv.z*wv.z + xv.w*wv.w;
      }
    }
#pragma unroll
    for (int e = 0; e < 8; ++e){
#pragma unroll
      for (int off = 32; off > 0; off >>= 1) l[e] += __shfl_xor(l[e], off);
      l[e] += br[e];
    }
    float m = l[0];
#pragma unroll
    for (int e = 1; e < 8; ++e) m = fmaxf(m, l[e]);
    float s = 0.f;
#pragma unroll
    for (int e = 0; e < 8; ++e){ l[e] = __expf(l[e] - m); s += l[e]; }
    const float inv = 1.f / s;
    if (lane == 0){
      float4 p0 = { l[0]*inv, l[1]*inv, l[2]*inv, l[3]*inv };
      float4 p1 = { l[4]*inv, l[5]*inv, l[6]*inv, l[7]*inv };
      *(float4*)(probs + (long)w*8)     = p0;
      *(float4*)(probs + (long)w*8 + 4) = p1;
    }
  }
}

#define FENCE()  __builtin_amdgcn_sched_barrier(0)
#define BAR()    do{ FENCE(); __builtin_amdgcn_s_barrier(); FENCE(); }while(0)
#define LGK0()   do{ asm volatile("s_waitcnt lgkmcnt(0)" ::: "memory"); FENCE(); }while(0)

// read one 16-row MFMA fragment: rows rbase..rbase+15, logical k-chunk c (0..7)
__device__ __forceinline__ s16x8 ld_frag(const u16* S, int rbase, int c, int ln){
  const int r = rbase + ln;
  return *(const s16x8*)(S + (r << 6) + ((c ^ (r & 7)) << 3));
}

// ---------- 256x256 GEMM, BK=64, 4-phase fine interleave (r9, verified) ----------
__device__ __forceinline__ void gemm256(const u16* __restrict__ Ag, long lda,
                                        const u16* __restrict__ Bg, long ldb,
                                        int NT, u16* lds, int tid,
                                        f32x4 (&acc)[8][4]){
  const int l  = tid & 63, w = tid >> 6;
  const int wr = w >> 2,  wc = w & 3;
  const int g4 = l >> 4,  ln = l & 15;

  const int rw = l >> 3;
  const int c8 = (l & 7) ^ rw;
  const u16* gA = Ag + (long)(w*8 + rw) * lda + c8*8;
  const u16* gB = Bg + (long)(w*8 + rw) * ldb + c8*8;
  u16* s0 = lds + w*512;
#define SA(par,T,rnd) gload_lds16(gA + (long)(T)*64 + (long)(rnd)*64*lda, s0 + (par)*32768 + (rnd)*4096)
#define SB(par,T,rnd) gload_lds16(gB + (long)(T)*64 + (long)(rnd)*64*ldb, s0 + (par)*32768 + 16384 + (rnd)*4096)

  // prologue: t0 full (8 loads), t1 early-half (4) -> wait t0 (t1's 4 in flight)
#pragma unroll
  for (int i = 0; i < 4; ++i) SA(0,0,i);
#pragma unroll
  for (int i = 0; i < 4; ++i) SB(0,0,i);
  SA(1,1,0); SB(1,1,0); SA(1,1,2); SB(1,1,1);
  FENCE();
  asm volatile("s_waitcnt vmcnt(4)" ::: "memory");
  BAR();

  for (int kt = 0; kt < NT; ++kt){
    const int par = kt & 1, oth = par ^ 1;
    const u16* As = lds + par * 32768;
    const u16* Bs = As + 16384;
    const bool st1 = (kt + 1 < NT), st2 = (kt + 2 < NT);
    s16x8 aL[4], aH[4], b0[4], b1[4];

    // ---- ph0 ----
#pragma unroll
    for (int ni = 0; ni < 4; ++ni) b0[ni] = ld_frag(Bs, wc*64 + ni*16, g4, ln);
#pragma unroll
    for (int mi = 0; mi < 4; ++mi) aL[mi] = ld_frag(As, wr*128 + mi*16, g4, ln);
    if (st1){ SA(oth, kt+1, 1); SB(oth, kt+1, 2); }
    BAR(); LGK0();
    __builtin_amdgcn_s_setprio(1);
#pragma unroll
    for (int mi = 0; mi < 4; ++mi)
#pragma unroll
      for (int ni = 0; ni < 4; ++ni)
        acc[mi][ni] = __builtin_amdgcn_mfma_f32_16x16x32_bf16(aL[mi], b0[ni], acc[mi][ni], 0, 0, 0);
    __builtin_amdgcn_s_setprio(0);
    BAR();

    // ---- ph1 ----
#pragma unroll
    for (int ni = 0; ni < 4; ++ni) b1[ni] = ld_frag(Bs, wc*64 + ni*16, 4 + g4, ln);
#pragma unroll
    for (int mi = 0; mi < 4; ++mi) aL[mi] = ld_frag(As, wr*128 + mi*16, 4 + g4, ln);
    if (st1){ SA(oth, kt+1, 3); SB(oth, kt+1, 3); }
    BAR(); LGK0();
    __builtin_amdgcn_s_setprio(1);
#pragma unroll
    for (int mi = 0; mi < 4; ++mi)
#pragma unroll
      for (int ni = 0; ni < 4; ++ni)
        acc[mi][ni] = __builtin_amdgcn_mfma_f32_16x16x32_bf16(aL[mi], b1[ni], acc[mi][ni], 0, 0, 0);
    __builtin_amdgcn_s_setprio(0);
    BAR();

    // ---- ph2 ----
#pragma unroll
    for (int mi = 0; mi < 4; ++mi) aH[mi] = ld_frag(As, wr*128 + 64 + mi*16, g4, ln);
    if (st2){ SA(par, kt+2, 0); SB(par, kt+2, 0); }
    BAR(); LGK0();
    __builtin_amdgcn_s_setprio(1);
#pragma unroll
    for (int mi = 0; mi < 4; ++mi)
#pragma unroll
      for (int ni = 0; ni < 4; ++ni)
        acc[mi+4][ni] = __builtin_amdgcn_mfma_f32_16x16x32_bf16(aH[mi], b0[ni], acc[mi+4][ni], 0, 0, 0);
    __builtin_amdgcn_s_setprio(0);
    BAR();

    // ---- ph3 + boundary ----
#pragma unroll
    for (int mi = 0; mi < 4; ++mi) aH[mi] = ld_frag(As, wr*128 + 64 + mi*16, 4 + g4, ln);
    if (st2){ SA(par, kt+2, 2); SB(par, kt+2, 1); }
    BAR(); LGK0();
    __builtin_amdgcn_s_setprio(1);
#pragma unroll
    for (int mi = 0; mi < 4; ++mi)
#pragma unroll
      for (int ni = 0; ni < 4; ++ni)
        acc[mi+4][ni] = __builtin_amdgcn_mfma_f32_16x16x32_bf16(aH[mi], b1[ni], acc[mi+4][ni], 0, 0, 0);
    __builtin_amdgcn_s_setprio(0);

    if (st1){
      FENCE();
      if (st2) asm volatile("s_waitcnt vmcnt(4)" ::: "memory");
      else     asm volatile("s_waitcnt vmcnt(0)" ::: "memory");
      BAR();
    }
  }
#undef SA
#undef SB
}

// ---------- paired dispatch (r9 verbatim): g2(e2, one token-half) + g1(e1, other half) ----------
__global__ __launch_bounds__(512, 2) void k_pair(const u16* __restrict__ xb,
                                                 const u16* __restrict__ w1b,
                                                 const float* __restrict__ b1,
                                                 const u16* __restrict__ w2b,
                                                 const float* __restrict__ b2,
                                                 const float* __restrict__ probs,
                                                 float* __restrict__ out,
                                                 const u16* __restrict__ hbR,
                                                 u16* __restrict__ hbW,
                                                 int e2, int t02,
                                                 int e1, int t01, int mt1, int n2){
  __shared__ alignas(16) u16 lds[65536];   // 128 KiB: 2 bufs x (A | B)
  const int tid = threadIdx.x;
  const int l  = tid & 63, w = tid >> 6;
  const int wr = w >> 2,  wc = w & 3;
  const int g4 = l >> 4,  ln = l & 15;
  const int bx = (int)blockIdx.x;
  f32x4 acc[8][4] = {};

  if (bx < n2){
    // ---- g2: XCD-chunked, y-fastest (3 N-tiles share the A-panel) ----
    const int wg = xcd_chunk(bx, n2);
    const int tx = wg / 3, ty = wg % 3;
    const int m0 = tx << 8, n0 = ty << 8;
    gemm256(hbR + (long)m0 * H_DIM, H_DIM,
            w2b + ((long)e2 * D_DIM + n0) * H_DIM, H_DIM,
            48, lds, tid, acc);
    float bias[4];
#pragma unroll
    for (int ni = 0; ni < 4; ++ni) bias[ni] = b2[(long)e2*D_DIM + n0 + wc*64 + ni*16 + ln];
#pragma unroll
    for (int mi = 0; mi < 8; ++mi){
#pragma unroll
      for (int j = 0; j < 4; ++j){
        const int gt = t02 + m0 + wr*128 + mi*16 + g4*4 + j;
        if (gt < (int)T_TOK){
          const float p = probs[(long)gt*8 + e2];
          float* dst = out + (long)gt * D_DIM + n0 + wc*64;
#pragma unroll
          for (int ni = 0; ni < 4; ++ni){
            const float v = p * (acc[mi][ni][j] + bias[ni]);
            if (e2 == 0) dst[ni*16 + ln] = v;
            else         dst[ni*16 + ln] += v;
          }
        }
      }
    }
  } else {
    // ---- g1: x-fastest chunk (B-panel reuse along chunk) ----
    const int n1 = (int)gridDim.x - n2;
    const int wg = xcd_chunk(bx - n2, n1);
    const int tx = wg % mt1, ty = wg / mt1;
    const int m0 = tx << 8, n0 = ty << 8;
    gemm256(xb + (long)(t01 + m0) * D_DIM, D_DIM,
            w1b + ((long)e1 * H_DIM + n0) * D_DIM, D_DIM,
            12, lds, tid, acc);
    float bias[4];
#pragma unroll
    for (int ni = 0; ni < 4; ++ni) bias[ni] = b1[(long)e1*H_DIM + n0 + wc*64 + ni*16 + ln];
#pragma unroll
    for (int mi = 0; mi < 8; ++mi){
#pragma unroll
      for (int j = 0; j < 4; ++j){
        const int r = m0 + wr*128 + mi*16 + g4*4 + j;     // half-local row
        u16* dst = hbW + (long)r * H_DIM + n0 + wc*64;
#pragma unroll
        for (int ni = 0; ni < 4; ++ni){
          const float v  = acc[mi][ni][j] + bias[ni];
          const float gl = v / (1.0f + __expf(-1.702f * v));  // quick_gelu
          dst[ni*16 + ln] = f2bf(gl);
        }
      }
    }
  }
}

// ---------- final dispatch: g2(7, half B) split-K=2, atomicAdd (starved dispatch) ----------
__global__ __launch_bounds__(512, 2) void k_g2split(const u16* __restrict__ w2b,
                                                    const float* __restrict__ b2,
                                                    const float* __restrict__ probs,
                                                    float* __restrict__ out,
                                                    const u16* __restrict__ hbR,
                                                    int e2, int t02, int n2){
  __shared__ alignas(16) u16 lds[65536];
  const int tid = threadIdx.x;
  const int l  = tid & 63, w = tid >> 6;
  const int wr = w >> 2,  wc = w & 3;
  const int g4 = l >> 4,  ln = l & 15;
  f32x4 acc[8][4] = {};

  const int wg = xcd_chunk((int)blockIdx.x, n2);
  const int ty = wg % 3;
  const int sp = (wg / 3) & 1;
  const int tx = wg / 6;
  const int m0 = tx << 8, n0 = ty << 8;
  gemm256(hbR + (long)m0 * H_DIM + sp*1536, H_DIM,
          w2b + ((long)e2 * D_DIM + n0) * H_DIM + sp*1536, H_DIM,
          24, lds, tid, acc);
  float bias[4];
#pragma unroll
  for (int ni = 0; ni < 4; ++ni)
    bias[ni] = (sp == 0) ? b2[(long)e2*D_DIM + n0 + wc*64 + ni*16 + ln] : 0.f;
#pragma unroll
  for (int mi = 0; mi < 8; ++mi){
#pragma unroll
    for (int j = 0; j < 4; ++j){
      const int gt = t02 + m0 + wr*128 + mi*16 + g4*4 + j;
      if (gt < (int)T_TOK){
        const float p = probs[(long)gt*8 + e2];
        float* dst = out + (long)gt * D_DIM + n0 + wc*64;
#pragma unroll
        for (int ni = 0; ni < 4; ++ni)
          atomicAdd(&dst[ni*16 + ln], p * (acc[mi][ni][j] + bias[ni]));
      }
    }
  }
}

// ---------- host ----------
extern "C" void kernel_launch(void* const* d_in, const int* in_sizes, int n_in,
                              void* d_out, int out_size, void* d_ws, size_t ws_size,
                              hipStream_t stream){
  const float* x  = (const float*)d_in[0];
  const float* W1 = (const float*)d_in[1];
  const float* b1 = (const float*)d_in[2];
  const float* W2 = (const float*)d_in[3];
  const float* b2 = (const float*)d_in[4];
  const float* Wr = (const float*)d_in[5];
  const float* br = (const float*)d_in[6];
  float* out = (float*)d_out;

  char* ws = (char*)d_ws;
  size_t off = 0;
  auto carve = [&](size_t bytes)->void*{
    void* p = ws + off; off += (bytes + 255) & ~(size_t)255; return p;
  };
  u16*   xb    = (u16*)  carve((size_t)M_PAD * D_DIM * 2);
  u16*   w1b   = (u16*)  carve((size_t)E_NUM * H_DIM * D_DIM * 2);
  u16*   w2b   = (u16*)  carve((size_t)E_NUM * D_DIM * H_DIM * 2);
  float* probs = (float*)carve((size_t)T_TOK * E_NUM * 4);
  u16*   hbA   = (u16*)  carve((size_t)8192 * H_DIM * 2);   // tokens [0, 8192)
  u16*   hbB   = (u16*)  carve((size_t)8448 * H_DIM * 2);   // tokens [8192, 16640)

  // merged prologue: conv x/W1/W2 + router in one dispatch
  k_pro<<<dim3(28784), dim3(256), 0, stream>>>(x, W1, W2, Wr, br, xb, w1b, w2b, probs);

  const int MTA = 32, MTB = 33;      // 256-row tile counts per token-half
  const int T0A = 0,  T0B = 8192;

  auto pair = [&](int e2, const u16* hbR, int t02, int mt2,
                  int e1, u16* hbW, int t01, int mt1){
    const int n2 = mt2 * 3;
    const int n1 = mt1 * 12;
    k_pair<<<dim3((unsigned)(n2 + n1)), dim3(512), 0, stream>>>(
        xb, w1b, b1, w2b, b2, probs, out, hbR, hbW,
        e2, t02, e1, t01, mt1, n2);
  };

  // ping-pong: D0: g1(0,A); D(2e+1): g2(e,A)+g1(e,B); D(2e+2): g2(e,B)+g1(e+1,A)
  pair(0, nullptr, 0, 0, 0, hbA, T0A, MTA);
  for (int e = 0; e < 8; ++e){
    pair(e, hbA, T0A, MTA, e, hbB, T0B, MTB);
    if (e < 7) pair(e, hbB, T0B, MTB, e + 1, hbA, T0A, MTA);
  }
  // D16: g2(7,B) alone -> split-K=2 + atomics (dedicated kernel, k_pair untouched)
  k_g2split<<<dim3((unsigned)(MTB * 6)), dim3(512), 0, stream>>>(
      w2b, b2, probs, out, hbB, 7, T0B, MTB * 6);
}

// Round 19
// 1758.973 us; speedup vs baseline: 1.4339x; 1.1180x over previous
//
#include <hip/hip_runtime.h>

typedef unsigned short u16;
typedef float f32x4 __attribute__((ext_vector_type(4)));
typedef short s16x8 __attribute__((ext_vector_type(8)));

#define T_TOK   16448L   // 257*64
#define D_DIM   768L
#define H_DIM   3072L
#define E_NUM   8L
#define M_PAD   16640L   // 65*256 ; halves: A=8192 rows (32 tiles), B=8448 rows (33 tiles)

// ---------- helpers ----------
__device__ __forceinline__ u16 f2bf(float f){
  unsigned u = __float_as_uint(f);
  u = u + 0x7FFFu + ((u >> 16) & 1u);          // RNE
  return (u16)(u >> 16);
}
__device__ __forceinline__ float bf2f(u16 u){
  return __uint_as_float((unsigned)u << 16);
}
__device__ __forceinline__ unsigned f2bf2(float a, float b){
  return (unsigned)f2bf(a) | ((unsigned)f2bf(b) << 16);
}

__device__ __forceinline__ void gload_lds16(const u16* g, u16* s){
  __builtin_amdgcn_global_load_lds((const __attribute__((address_space(1))) void*)g,
                                   (__attribute__((address_space(3))) void*)s,
                                   16, 0, 0);
}

// bijective XCD chunking (m204)
__device__ __forceinline__ int xcd_chunk(int idx, int n){
  const int q = n >> 3, r = n & 7, x = idx & 7;
  return (x < r ? x*(q+1) : r*(q+1) + (x-r)*q) + (idx >> 3);
}

// ---------- zero-init out half-B (needed for D16 atomics) ----------
__global__ void k_initb(float* __restrict__ outB, long n4){
  long i = (long)blockIdx.x * blockDim.x + threadIdx.x;
  long st = (long)gridDim.x * blockDim.x;
  const float4 z = {0.f, 0.f, 0.f, 0.f};
  for (long v = i; v < n4; v += st) *(float4*)(outB + (v<<2)) = z;
}

// ---------- merged prologue: conv x / conv W1 / conv W2 / router (r14, verified) ----------
__global__ __launch_bounds__(256) void k_pro(const float* __restrict__ x,
                                             const float* __restrict__ W1,
                                             const float* __restrict__ W2,
                                             const float* __restrict__ Wr,
                                             const float* __restrict__ br,
                                             u16* __restrict__ xb,
                                             u16* __restrict__ w1b,
                                             u16* __restrict__ w2b,
                                             float* __restrict__ probs){
  const int bx = (int)blockIdx.x, tid = threadIdx.x;
  if (bx < 6240){
    const long base = ((long)bx*256 + tid) << 3;
    uint4 o;
    if (base < T_TOK*D_DIM){
      const float4 f0 = *(const float4*)(x + base);
      const float4 f1 = *(const float4*)(x + base + 4);
      o.x = f2bf2(f0.x, f0.y); o.y = f2bf2(f0.z, f0.w);
      o.z = f2bf2(f1.x, f1.y); o.w = f2bf2(f1.z, f1.w);
    } else { o.x = o.y = o.z = o.w = 0u; }
    *(uint4*)(xb + base) = o;
  } else if (bx < 24672){
    const int  wsel = (bx < 15456) ? 0 : 1;
    const long base = ((long)(bx - (wsel ? 15456 : 6240))*256 + tid) << 3;
    const float* src = wsel ? W2 : W1;
    u16* dst = wsel ? w2b : w1b;
    const float4 f0 = *(const float4*)(src + base);
    const float4 f1 = *(const float4*)(src + base + 4);
    uint4 o;
    o.x = f2bf2(f0.x, f0.y); o.y = f2bf2(f0.z, f0.w);
    o.z = f2bf2(f1.x, f1.y); o.w = f2bf2(f1.z, f1.w);
    *(uint4*)(dst + base) = o;
  } else {
    const int w = (int)(((long)(bx - 24672)*256 + tid) >> 6);
    const int lane = tid & 63;
    if (w >= (int)T_TOK) return;
    const float* xr = x + (long)w * D_DIM;
    float l[8];
#pragma unroll
    for (int e = 0; e < 8; ++e) l[e] = 0.f;
#pragma unroll
    for (int c = 0; c < 3; ++c){
      const float4 xv = *(const float4*)(xr + c*256 + lane*4);
#pragma unroll
      for (int e = 0; e < 8; ++e){
        const float4 wv = *(const float4*)(Wr + (long)e*D_DIM + c*256 + lane*4);
        l[e] += xv.x*wv.x + xv.y*wv.y + xv.z*wv.z + xv.w*wv.w;
      }
    }
#pragma unroll
    for (int e = 0; e < 8; ++e){
#pragma unroll
      for (int off = 32; off > 0; off >>= 1) l[e] += __shfl_xor(l[e], off);
      l[e] += br[e];
    }
    float m = l[0];
#pragma unroll
    for (int e = 1; e < 8; ++e) m = fmaxf(m, l[e]);
    float s = 0.f;
#pragma unroll
    for (int e = 0; e < 8; ++e){ l[e] = __expf(l[e] - m); s += l[e]; }
    const float inv = 1.f / s;
    if (lane == 0){
      float4 p0 = { l[0]*inv, l[1]*inv, l[2]*inv, l[3]*inv };
      float4 p1 = { l[4]*inv, l[5]*inv, l[6]*inv, l[7]*inv };
      *(float4*)(probs + (long)w*8)     = p0;
      *(float4*)(probs + (long)w*8 + 4) = p1;
    }
  }
}

#define FENCE()  __builtin_amdgcn_sched_barrier(0)
#define BAR()    do{ FENCE(); __builtin_amdgcn_s_barrier(); FENCE(); }while(0)
#define LGK0()   do{ asm volatile("s_waitcnt lgkmcnt(0)" ::: "memory"); FENCE(); }while(0)

// read one 16-row MFMA fragment: rows rbase..rbase+15, logical k-chunk c (0..7)
__device__ __forceinline__ s16x8 ld_frag(const u16* S, int rbase, int c, int ln){
  const int r = rbase + ln;
  return *(const s16x8*)(S + (r << 6) + ((c ^ (r & 7)) << 3));
}

// ---------- 256x256 GEMM, BK=64, 4-phase fine interleave (r9, verified) ----------
__device__ __forceinline__ void gemm256(const u16* __restrict__ Ag, long lda,
                                        const u16* __restrict__ Bg, long ldb,
                                        int NT, u16* lds, int tid,
                                        f32x4 (&acc)[8][4]){
  const int l  = tid & 63, w = tid >> 6;
  const int wr = w >> 2,  wc = w & 3;
  const int g4 = l >> 4,  ln = l & 15;

  const int rw = l >> 3;
  const int c8 = (l & 7) ^ rw;
  const u16* gA = Ag + (long)(w*8 + rw) * lda + c8*8;
  const u16* gB = Bg + (long)(w*8 + rw) * ldb + c8*8;
  u16* s0 = lds + w*512;
#define SA(par,T,rnd) gload_lds16(gA + (long)(T)*64 + (long)(rnd)*64*lda, s0 + (par)*32768 + (rnd)*4096)
#define SB(par,T,rnd) gload_lds16(gB + (long)(T)*64 + (long)(rnd)*64*ldb, s0 + (par)*32768 + 16384 + (rnd)*4096)

  // prologue: t0 full (8 loads), t1 early-half (4) -> wait t0 (t1's 4 in flight)
#pragma unroll
  for (int i = 0; i < 4; ++i) SA(0,0,i);
#pragma unroll
  for (int i = 0; i < 4; ++i) SB(0,0,i);
  SA(1,1,0); SB(1,1,0); SA(1,1,2); SB(1,1,1);
  FENCE();
  asm volatile("s_waitcnt vmcnt(4)" ::: "memory");
  BAR();

  for (int kt = 0; kt < NT; ++kt){
    const int par = kt & 1, oth = par ^ 1;
    const u16* As = lds + par * 32768;
    const u16* Bs = As + 16384;
    const bool st1 = (kt + 1 < NT), st2 = (kt + 2 < NT);
    s16x8 aL[4], aH[4], b0[4], b1[4];

    // ---- ph0 ----
#pragma unroll
    for (int ni = 0; ni < 4; ++ni) b0[ni] = ld_frag(Bs, wc*64 + ni*16, g4, ln);
#pragma unroll
    for (int mi = 0; mi < 4; ++mi) aL[mi] = ld_frag(As, wr*128 + mi*16, g4, ln);
    if (st1){ SA(oth, kt+1, 1); SB(oth, kt+1, 2); }
    BAR(); LGK0();
    __builtin_amdgcn_s_setprio(1);
#pragma unroll
    for (int mi = 0; mi < 4; ++mi)
#pragma unroll
      for (int ni = 0; ni < 4; ++ni)
        acc[mi][ni] = __builtin_amdgcn_mfma_f32_16x16x32_bf16(aL[mi], b0[ni], acc[mi][ni], 0, 0, 0);
    __builtin_amdgcn_s_setprio(0);
    BAR();

    // ---- ph1 ----
#pragma unroll
    for (int ni = 0; ni < 4; ++ni) b1[ni] = ld_frag(Bs, wc*64 + ni*16, 4 + g4, ln);
#pragma unroll
    for (int mi = 0; mi < 4; ++mi) aL[mi] = ld_frag(As, wr*128 + mi*16, 4 + g4, ln);
    if (st1){ SA(oth, kt+1, 3); SB(oth, kt+1, 3); }
    BAR(); LGK0();
    __builtin_amdgcn_s_setprio(1);
#pragma unroll
    for (int mi = 0; mi < 4; ++mi)
#pragma unroll
      for (int ni = 0; ni < 4; ++ni)
        acc[mi][ni] = __builtin_amdgcn_mfma_f32_16x16x32_bf16(aL[mi], b1[ni], acc[mi][ni], 0, 0, 0);
    __builtin_amdgcn_s_setprio(0);
    BAR();

    // ---- ph2 ----
#pragma unroll
    for (int mi = 0; mi < 4; ++mi) aH[mi] = ld_frag(As, wr*128 + 64 + mi*16, g4, ln);
    if (st2){ SA(par, kt+2, 0); SB(par, kt+2, 0); }
    BAR(); LGK0();
    __builtin_amdgcn_s_setprio(1);
#pragma unroll
    for (int mi = 0; mi < 4; ++mi)
#pragma unroll
      for (int ni = 0; ni < 4; ++ni)
        acc[mi+4][ni] = __builtin_amdgcn_mfma_f32_16x16x32_bf16(aH[mi], b0[ni], acc[mi+4][ni], 0, 0, 0);
    __builtin_amdgcn_s_setprio(0);
    BAR();

    // ---- ph3 + boundary ----
#pragma unroll
    for (int mi = 0; mi < 4; ++mi) aH[mi] = ld_frag(As, wr*128 + 64 + mi*16, 4 + g4, ln);
    if (st2){ SA(par, kt+2, 2); SB(par, kt+2, 1); }
    BAR(); LGK0();
    __builtin_amdgcn_s_setprio(1);
#pragma unroll
    for (int mi = 0; mi < 4; ++mi)
#pragma unroll
      for (int ni = 0; ni < 4; ++ni)
        acc[mi+4][ni] = __builtin_amdgcn_mfma_f32_16x16x32_bf16(aH[mi], b1[ni], acc[mi+4][ni], 0, 0, 0);
    __builtin_amdgcn_s_setprio(0);

    if (st1){
      FENCE();
      if (st2) asm volatile("s_waitcnt vmcnt(4)" ::: "memory");
      else     asm volatile("s_waitcnt vmcnt(0)" ::: "memory");
      BAR();
    }
  }
#undef SA
#undef SB
}

// ---------- paired dispatch: g2(e2, one token-half) + g1(e1, other half) ----------
// Expert accumulation in bf16 scratch a16:
//   e2==0 : a16 = bf16(p*(acc+bias))                (store)
//   e2 1-6: a16 = bf16(a16 + p*(acc+bias))          (bf16 RMW, half the bytes)
//   e2==7 : out = float(a16) + p*(acc+bias)         (fused fp32 finalize; half A only)
__global__ __launch_bounds__(512, 2) void k_pair(const u16* __restrict__ xb,
                                                 const u16* __restrict__ w1b,
                                                 const float* __restrict__ b1,
                                                 const u16* __restrict__ w2b,
                                                 const float* __restrict__ b2,
                                                 const float* __restrict__ probs,
                                                 float* __restrict__ out,
                                                 u16* __restrict__ a16,
                                                 const u16* __restrict__ hbR,
                                                 u16* __restrict__ hbW,
                                                 int e2, int t02,
                                                 int e1, int t01, int mt1, int n2){
  __shared__ alignas(16) u16 lds[65536];   // 128 KiB: 2 bufs x (A | B)
  const int tid = threadIdx.x;
  const int l  = tid & 63, w = tid >> 6;
  const int wr = w >> 2,  wc = w & 3;
  const int g4 = l >> 4,  ln = l & 15;
  const int bx = (int)blockIdx.x;
  f32x4 acc[8][4] = {};

  if (bx < n2){
    // ---- g2: XCD-chunked, y-fastest (3 N-tiles share the A-panel) ----
    const int wg = xcd_chunk(bx, n2);
    const int tx = wg / 3, ty = wg % 3;
    const int m0 = tx << 8, n0 = ty << 8;
    gemm256(hbR + (long)m0 * H_DIM, H_DIM,
            w2b + ((long)e2 * D_DIM + n0) * H_DIM, H_DIM,
            48, lds, tid, acc);
    float bias[4];
#pragma unroll
    for (int ni = 0; ni < 4; ++ni) bias[ni] = b2[(long)e2*D_DIM + n0 + wc*64 + ni*16 + ln];
#pragma unroll
    for (int mi = 0; mi < 8; ++mi){
#pragma unroll
      for (int j = 0; j < 4; ++j){
        const int gt = t02 + m0 + wr*128 + mi*16 + g4*4 + j;
        if (gt < (int)T_TOK){
          const float p = probs[(long)gt*8 + e2];
          const long ob = (long)gt * D_DIM + n0 + wc*64;
          if (e2 == 0){
            u16* d = a16 + ob;
#pragma unroll
            for (int ni = 0; ni < 4; ++ni)
              d[ni*16 + ln] = f2bf(p * (acc[mi][ni][j] + bias[ni]));
          } else if (e2 == 7){
            float* d = out + ob;
            const u16* s = a16 + ob;
#pragma unroll
            for (int ni = 0; ni < 4; ++ni)
              d[ni*16 + ln] = bf2f(s[ni*16 + ln]) + p * (acc[mi][ni][j] + bias[ni]);
          } else {
            u16* d = a16 + ob;
#pragma unroll
            for (int ni = 0; ni < 4; ++ni){
              const int o = ni*16 + ln;
              d[o] = f2bf(bf2f(d[o]) + p * (acc[mi][ni][j] + bias[ni]));
            }
          }
        }
      }
    }
  } else {
    // ---- g1: x-fastest chunk (B-panel reuse along chunk) ----
    const int n1 = (int)gridDim.x - n2;
    const int wg = xcd_chunk(bx - n2, n1);
    const int tx = wg % mt1, ty = wg / mt1;
    const int m0 = tx << 8, n0 = ty << 8;
    gemm256(xb + (long)(t01 + m0) * D_DIM, D_DIM,
            w1b + ((long)e1 * H_DIM + n0) * D_DIM, D_DIM,
            12, lds, tid, acc);
    float bias[4];
#pragma unroll
    for (int ni = 0; ni < 4; ++ni) bias[ni] = b1[(long)e1*H_DIM + n0 + wc*64 + ni*16 + ln];
#pragma unroll
    for (int mi = 0; mi < 8; ++mi){
#pragma unroll
      for (int j = 0; j < 4; ++j){
        const int r = m0 + wr*128 + mi*16 + g4*4 + j;     // half-local row
        u16* dst = hbW + (long)r * H_DIM + n0 + wc*64;
#pragma unroll
        for (int ni = 0; ni < 4; ++ni){
          const float v  = acc[mi][ni][j] + bias[ni];
          const float gl = v / (1.0f + __expf(-1.702f * v));  // quick_gelu
          dst[ni*16 + ln] = f2bf(gl);
        }
      }
    }
  }
}

// ---------- final dispatch: g2(7, half B) split-K=2, fused finalize via atomics ----------
// out(half B) pre-zeroed. sp0 adds float(a16) + p*(acc+bias); sp1 adds p*acc.
__global__ __launch_bounds__(512, 2) void k_g2split(const u16* __restrict__ w2b,
                                                    const float* __restrict__ b2,
                                                    const float* __restrict__ probs,
                                                    float* __restrict__ out,
                                                    const u16* __restrict__ a16,
                                                    const u16* __restrict__ hbR,
                                                    int e2, int t02, int n2){
  __shared__ alignas(16) u16 lds[65536];
  const int tid = threadIdx.x;
  const int l  = tid & 63, w = tid >> 6;
  const int wr = w >> 2,  wc = w & 3;
  const int g4 = l >> 4,  ln = l & 15;
  f32x4 acc[8][4] = {};

  const int wg = xcd_chunk((int)blockIdx.x, n2);
  const int ty = wg % 3;
  const int sp = (wg / 3) & 1;
  const int tx = wg / 6;
  const int m0 = tx << 8, n0 = ty << 8;
  gemm256(hbR + (long)m0 * H_DIM + sp*1536, H_DIM,
          w2b + ((long)e2 * D_DIM + n0) * H_DIM + sp*1536, H_DIM,
          24, lds, tid, acc);
  float bias[4];
#pragma unroll
  for (int ni = 0; ni < 4; ++ni)
    bias[ni] = (sp == 0) ? b2[(long)e2*D_DIM + n0 + wc*64 + ni*16 + ln] : 0.f;
#pragma unroll
  for (int mi = 0; mi < 8; ++mi){
#pragma unroll
    for (int j = 0; j < 4; ++j){
      const int gt = t02 + m0 + wr*128 + mi*16 + g4*4 + j;
      if (gt < (int)T_TOK){
        const float p = probs[(long)gt*8 + e2];
        const long ob = (long)gt * D_DIM + n0 + wc*64;
        float* d = out + ob;
        if (sp == 0){
          const u16* s = a16 + ob;
#pragma unroll
          for (int ni = 0; ni < 4; ++ni)
            atomicAdd(&d[ni*16 + ln], bf2f(s[ni*16 + ln]) + p * (acc[mi][ni][j] + bias[ni]));
        } else {
#pragma unroll
          for (int ni = 0; ni < 4; ++ni)
            atomicAdd(&d[ni*16 + ln], p * acc[mi][ni][j]);
        }
      }
    }
  }
}

// ---------- host ----------
extern "C" void kernel_launch(void* const* d_in, const int* in_sizes, int n_in,
                              void* d_out, int out_size, void* d_ws, size_t ws_size,
                              hipStream_t stream){
  const float* x  = (const float*)d_in[0];
  const float* W1 = (const float*)d_in[1];
  const float* b1 = (const float*)d_in[2];
  const float* W2 = (const float*)d_in[3];
  const float* b2 = (const float*)d_in[4];
  const float* Wr = (const float*)d_in[5];
  const float* br = (const float*)d_in[6];
  float* out = (float*)d_out;

  char* ws = (char*)d_ws;
  size_t off = 0;
  auto carve = [&](size_t bytes)->void*{
    void* p = ws + off; off += (bytes + 255) & ~(size_t)255; return p;
  };
  u16*   xb    = (u16*)  carve((size_t)M_PAD * D_DIM * 2);
  u16*   w1b   = (u16*)  carve((size_t)E_NUM * H_DIM * D_DIM * 2);
  u16*   w2b   = (u16*)  carve((size_t)E_NUM * D_DIM * H_DIM * 2);
  float* probs = (float*)carve((size_t)T_TOK * E_NUM * 4);
  u16*   hbA   = (u16*)  carve((size_t)8192 * H_DIM * 2);   // tokens [0, 8192)
  u16*   hbB   = (u16*)  carve((size_t)8448 * H_DIM * 2);   // tokens [8192, 16640)
  u16*   a16   = (u16*)  carve((size_t)T_TOK * D_DIM * 2);  // bf16 expert accumulator

  // zero out half-B (D16 atomics accumulate into it) + merged prologue
  k_initb<<<dim3(512), dim3(256), 0, stream>>>(out + 8192*D_DIM,
                                               ((T_TOK - 8192) * D_DIM) >> 2);
  k_pro<<<dim3(28784), dim3(256), 0, stream>>>(x, W1, W2, Wr, br, xb, w1b, w2b, probs);

  const int MTA = 32, MTB = 33;      // 256-row tile counts per token-half
  const int T0A = 0,  T0B = 8192;

  auto pair = [&](int e2, const u16* hbR, int t02, int mt2,
                  int e1, u16* hbW, int t01, int mt1){
    const int n2 = mt2 * 3;
    const int n1 = mt1 * 12;
    k_pair<<<dim3((unsigned)(n2 + n1)), dim3(512), 0, stream>>>(
        xb, w1b, b1, w2b, b2, probs, out, a16, hbR, hbW,
        e2, t02, e1, t01, mt1, n2);
  };

  // ping-pong: D0: g1(0,A); D(2e+1): g2(e,A)+g1(e,B); D(2e+2): g2(e,B)+g1(e+1,A)
  pair(0, nullptr, 0, 0, 0, hbA, T0A, MTA);
  for (int e = 0; e < 8; ++e){
    pair(e, hbA, T0A, MTA, e, hbB, T0B, MTB);
    if (e < 7) pair(e, hbB, T0B, MTB, e + 1, hbA, T0A, MTA);
  }
  // D16: g2(7,B) alone -> split-K=2 + atomics, fused bf16->fp32 finalize
  k_g2split<<<dim3((unsigned)(MTB * 6)), dim3(512), 0, stream>>>(
      w2b, b2, probs, out, a16, hbB, 7, T0B, MTB * 6);
}